// Round 14
// baseline (1415.284 us; speedup 1.0000x reference)
//
#include <hip/hip_runtime.h>
#include <hip/hip_bf16.h>
#include <hip/hip_cooperative_groups.h>
#include <stdint.h>

#define NN 100000
#define EE 1600000
#define IND 128
#define HD 128
#define EM 64
#define KC 100
#define BN_EPS 1e-5f
#define BKT 512
#define NBK ((NN + BKT - 1) / BKT)      // 196 buckets (dst >> 9)
#define BSTRIDE 16384                    // slots per bucket in pbuf
#define BN2_ROWS 256
#define NB_PART ((EE + 2047) / 2048)     // 782
#define NB_GEMM ((NN + 63) / 64)         // 1563
#define NB_GATH (NN / 4)                 // 25000
#define NB_BN   ((NN + BN2_ROWS - 1) / BN2_ROWS)  // 391

typedef _Float16 h8 __attribute__((ext_vector_type(8)));
typedef float f4v __attribute__((ext_vector_type(4)));

// bf16 helpers: low short = first element
__device__ __forceinline__ unsigned bf16pk(float lo, float hi){
  unsigned a = __float_as_uint(lo), b = __float_as_uint(hi);
  a += 0x7fffu + ((a >> 16) & 1u);
  b += 0x7fffu + ((b >> 16) & 1u);
  return (a >> 16) | (b & 0xffff0000u);
}
__device__ __forceinline__ unsigned short bf16s(float v){
  unsigned u = __float_as_uint(v);
  u += 0x7fffu + ((u >> 16) & 1u);
  return (unsigned short)(u >> 16);
}
__device__ __forceinline__ void bfacc(float4& a, uint2 v){
  a.x += __uint_as_float(v.x << 16);
  a.y += __uint_as_float(v.x & 0xffff0000u);
  a.z += __uint_as_float(v.y << 16);
  a.w += __uint_as_float(v.y & 0xffff0000u);
}

// -------- W fragment prep helper (bijective-k trick; see round-4 notes) -----
__device__ __forceinline__ void wprep_one(const float* __restrict__ W, int N, int nt_cnt,
                                          unsigned short* __restrict__ wf, int e){
  int total = 4*nt_cnt*64;
  if (e >= total) return;
  int lane = e & 63;
  int nt = (e >> 6) % nt_cnt;
  int ks = (e >> 6) / nt_cnt;
  int n = nt*16 + (lane & 15);
  int kb = ks*32 + (lane >> 4)*4;
  unsigned short out[8];
  #pragma unroll
  for (int j = 0; j < 8; ++j){
    int k = kb + (j>>2)*16 + (j&3);
    _Float16 h = (_Float16)W[k*N + n];
    out[j] = *(unsigned short*)&h;
  }
  *(uint4*)&wf[(size_t)e*8] = *(const uint4*)out;
}

__device__ __forceinline__ void cprep_one(const float* __restrict__ ctr,
                                          const float* __restrict__ temp,
                                          unsigned short* __restrict__ cf, int e){
  if (e >= 2*7*64) return;
  float invT = 1.0f / temp[0];
  int lane = e & 63;
  int nt = (e >> 6) % 7;
  int ks = (e >> 6) / 7;
  int n = nt*16 + (lane & 15);
  int kb = ks*32 + (lane >> 4)*4;
  unsigned short o[8];
  #pragma unroll
  for (int j = 0; j < 8; ++j){
    int k = kb + (j>>2)*16 + (j&3);
    float v = (n < KC) ? ctr[n*EM + k]*invT : 0.f;
    _Float16 h = (_Float16)v;
    o[j] = *(unsigned short*)&h;
  }
  *(uint4*)&cf[(size_t)e*8] = *(const uint4*)o;
}

// =================== cooperative mega-kernel (all 9 phases) =================
__global__ __launch_bounds__(256, 4) void k_mega(
    const float* __restrict__ x, const int* __restrict__ ei,
    const float* __restrict__ W1, const float* __restrict__ b1,
    const float* __restrict__ gamma, const float* __restrict__ beta,
    const float* __restrict__ W2, const float* __restrict__ b2v,
    const float* __restrict__ ctr, const float* __restrict__ temp,
    float* __restrict__ dis, int* __restrict__ rowptr, int* __restrict__ esrc,
    int* __restrict__ gcur, unsigned short* __restrict__ w1f,
    unsigned short* __restrict__ w2f, unsigned short* __restrict__ cf,
    int2* __restrict__ pbuf, unsigned short* __restrict__ h1s,
    unsigned short* __restrict__ hg, unsigned short* __restrict__ h2s,
    float* __restrict__ sums, float* __restrict__ sumsq,
    float* __restrict__ out)
{
  cooperative_groups::grid_group gg = cooperative_groups::this_grid();
  __shared__ __align__(16) char smem[8192];
  int t = threadIdx.x;
  const int NBLK = gridDim.x;

  // ---- P0: zero gcur/sums/sumsq + W1/W2/centers fragment prep (16 vb) ----
  for (int vb = blockIdx.x; vb < 16; vb += NBLK){
    if (vb < 8){
      wprep_one(W1, HD, 8, w1f, vb*256 + t);
      if (vb == 0) gcur[t] = 0;
      if (vb == 1 && t < HD){ sums[t] = 0.f; sumsq[t] = 0.f; }
    } else if (vb < 12){
      wprep_one(W2, EM, 4, w2f, (vb-8)*256 + t);
    } else {
      cprep_one(ctr, temp, cf, (vb-12)*256 + t);
    }
  }
  __threadfence(); gg.sync();

  // ---- P1: edge partition into fixed-stride buckets (782 vb) ----
  {
    int* lh = (int*)smem; int* lcur = lh + NBK;
    for (int vb = blockIdx.x; vb < NB_PART; vb += NBLK){
      for (int i = t; i < NBK; i += 256) lh[i] = 0;
      __syncthreads();
      int e0 = vb*2048;
      int se[8], de[8];
      #pragma unroll
      for (int i = 0; i < 8; ++i){
        int e = e0 + i*256 + t;
        if (e < EE){
          se[i] = ei[e]; de[i] = ei[EE + e];
          atomicAdd(&lh[de[i] >> 9], 1);
        }
      }
      __syncthreads();
      for (int i = t; i < NBK; i += 256)
        lcur[i] = lh[i] ? atomicAdd(&gcur[i], lh[i]) : 0;
      __syncthreads();
      #pragma unroll
      for (int i = 0; i < 8; ++i){
        int e = e0 + i*256 + t;
        if (e < EE){
          int b = de[i] >> 9;
          int pos = atomicAdd(&lcur[b], 1);
          pbuf[(size_t)b*BSTRIDE + pos] = make_int2(se[i], de[i]);
        }
      }
      __syncthreads();   // protect smem reuse across vb
    }
  }
  __threadfence(); gg.sync();

  // ---- P2: per-bucket CSR fill (196 vb) ----
  {
    int* lcnt = (int*)smem; int* ls = lcnt + BKT; int* sb = ls + 256;
    for (int vb = blockIdx.x; vb < NBK; vb += NBLK){
      int n0 = vb*BKT;
      int v = (t < NBK) ? gcur[t] : 0;
      ls[t] = v; __syncthreads();
      #pragma unroll
      for (int off = 1; off < 256; off <<= 1){
        int xx = (t >= off) ? ls[t-off] : 0;
        __syncthreads();
        ls[t] += xx;
        __syncthreads();
      }
      if (t == vb){ sb[0] = ls[t] - v; sb[1] = v; }
      if (vb == 0 && t == 0) rowptr[NN] = EE;
      __syncthreads();
      int e0 = sb[0], cnt = sb[1];
      lcnt[2*t] = 0; lcnt[2*t+1] = 0;
      __syncthreads();
      const int2* pb = pbuf + (size_t)vb*BSTRIDE;
      for (int e = t; e < cnt; e += 256)
        atomicAdd(&lcnt[pb[e].y - n0], 1);
      __syncthreads();
      int v0 = lcnt[2*t], v1 = lcnt[2*t+1];
      int s = v0 + v1;
      ls[t] = s; __syncthreads();
      #pragma unroll
      for (int off = 1; off < 256; off <<= 1){
        int xx = (t >= off) ? ls[t-off] : 0;
        __syncthreads();
        ls[t] += xx;
        __syncthreads();
      }
      int run = ls[t] - s;
      if (n0 + 2*t < NN){
        rowptr[n0 + 2*t] = e0 + run;
        dis[n0 + 2*t] = rsqrtf((float)v0 + 1.0f);
      }
      if (n0 + 2*t + 1 < NN){
        rowptr[n0 + 2*t + 1] = e0 + run + v0;
        dis[n0 + 2*t + 1] = rsqrtf((float)v1 + 1.0f);
      }
      lcnt[2*t] = run; lcnt[2*t+1] = run + v0;
      __syncthreads();
      for (int e = t; e < cnt; e += 256){
        int2 p = pb[e];
        int pos = atomicAdd(&lcnt[p.y - n0], 1);
        esrc[e0 + pos] = p.x;
      }
      __syncthreads();   // protect smem reuse across vb
    }
  }
  __threadfence(); gg.sync();

  // ---- P3: GEMM1 (MFMA f16): h1s = bf16((x@W1)*dis) (1563 vb) ----
  {
    int w = t >> 6, l = t & 63;
    int kg = (l >> 4)*4;
    int oc = l & 15;
    for (int vb = blockIdx.x; vb < NB_GEMM; vb += NBLK){
      int arow = vb*64 + w*16 + (l & 15);
      const float* xr = x + (size_t)min(arow, NN-1)*IND;
      f4v acc[8];
      #pragma unroll
      for (int i = 0; i < 8; ++i) acc[i] = (f4v){0.f,0.f,0.f,0.f};
      #pragma unroll
      for (int ks = 0; ks < 4; ++ks){
        float4 a0 = *(const float4*)&xr[ks*32 + kg];
        float4 a1 = *(const float4*)&xr[ks*32 + 16 + kg];
        h8 af;
        af[0]=(_Float16)a0.x; af[1]=(_Float16)a0.y; af[2]=(_Float16)a0.z; af[3]=(_Float16)a0.w;
        af[4]=(_Float16)a1.x; af[5]=(_Float16)a1.y; af[6]=(_Float16)a1.z; af[7]=(_Float16)a1.w;
        const unsigned short* wb = w1f + ((size_t)(ks*8)*64 + l)*8;
        #pragma unroll
        for (int nt = 0; nt < 8; ++nt){
          h8 bf = *(const h8*)(wb + (size_t)nt*64*8);
          acc[nt] = __builtin_amdgcn_mfma_f32_16x16x32_f16(af, bf, acc[nt], 0, 0, 0);
        }
      }
      int orow0 = vb*64 + w*16 + (l >> 4)*4;
      #pragma unroll
      for (int r = 0; r < 4; ++r){
        int rr = orow0 + r;
        if (rr < NN){
          float sc = dis[rr];
          #pragma unroll
          for (int nt = 0; nt < 8; ++nt)
            h1s[(size_t)rr*HD + nt*16 + oc] = bf16s(acc[nt][r]*sc);
        }
      }
    }
  }
  __threadfence(); gg.sync();

  // ---- P4: GCN1 gather (25000 vb) ----
  {
    int w = t >> 6, lane = t & 63;
    int half = lane >> 5;
    int q = lane & 31;
    for (int vb = blockIdx.x; vb < NB_GATH; vb += NBLK){
      int d = vb*4 + w;
      float dd = dis[d];
      float4 a = make_float4(0.f,0.f,0.f,0.f);
      if (half == 0){
        bfacc(a, *(const uint2*)&h1s[(size_t)d*HD + q*4]);   // self loop
      }
      int p0 = rowptr[d], p1 = rowptr[d+1];
      for (int base = p0; base < p1; base += 64){
        int idx = base + lane;
        int s_l = (idx < p1) ? esrc[idx] : 0;
        int m = min(64, p1 - base);             // wave-uniform
        int mm8 = m & ~7;
        for (int jb = 0; jb < mm8; jb += 8){
          int s0 = __shfl(s_l, jb + half);
          int s1 = __shfl(s_l, jb + 2 + half);
          int s2 = __shfl(s_l, jb + 4 + half);
          int s3 = __shfl(s_l, jb + 6 + half);
          uint2 v0 = *(const uint2*)&h1s[(size_t)s0*HD + q*4];
          uint2 v1 = *(const uint2*)&h1s[(size_t)s1*HD + q*4];
          uint2 v2 = *(const uint2*)&h1s[(size_t)s2*HD + q*4];
          uint2 v3 = *(const uint2*)&h1s[(size_t)s3*HD + q*4];
          bfacc(a, v0); bfacc(a, v1); bfacc(a, v2); bfacc(a, v3);
        }
        for (int j = mm8; j < m; j += 2){
          int jj = j + half;
          int s = __shfl(s_l, jj);
          if (jj < m){
            bfacc(a, *(const uint2*)&h1s[(size_t)s*HD + q*4]);
          }
        }
      }
      a.x += __shfl_xor(a.x, 32); a.y += __shfl_xor(a.y, 32);
      a.z += __shfl_xor(a.z, 32); a.w += __shfl_xor(a.w, 32);
      if (half == 0){
        float4 b = *(const float4*)&b1[q*4];
        float vx = a.x*dd + b.x, vy = a.y*dd + b.y;
        float vz = a.z*dd + b.z, vw = a.w*dd + b.w;
        uint2 o; o.x = bf16pk(vx, vy); o.y = bf16pk(vz, vw);
        *(uint2*)&hg[(size_t)d*HD + q*4] = o;
      }
    }
  }
  __threadfence(); gg.sync();

  // ---- P5: BatchNorm stats (391 vb) ----
  {
    float* lsum = (float*)smem;          // [8][HD]
    float* lsq  = lsum + 8*HD;           // [8][HD]
    int rg = t >> 5, c4 = (t & 31)*4;
    for (int vb = blockIdx.x; vb < NB_BN; vb += NBLK){
      int r1 = min(vb*BN2_ROWS + BN2_ROWS, NN);
      float4 s = make_float4(0.f,0.f,0.f,0.f), q = make_float4(0.f,0.f,0.f,0.f);
      for (int r = vb*BN2_ROWS + rg; r < r1; r += 8){
        uint2 u = *(const uint2*)&hg[(size_t)r*HD + c4];
        float x0 = __uint_as_float(u.x << 16), x1 = __uint_as_float(u.x & 0xffff0000u);
        float x2 = __uint_as_float(u.y << 16), x3 = __uint_as_float(u.y & 0xffff0000u);
        s.x += x0; s.y += x1; s.z += x2; s.w += x3;
        q.x += x0*x0; q.y += x1*x1; q.z += x2*x2; q.w += x3*x3;
      }
      *(float4*)&lsum[rg*HD + c4] = s;
      *(float4*)&lsq[rg*HD + c4]  = q;
      __syncthreads();
      #pragma unroll
      for (int off = 4; off >= 1; off >>= 1){
        if (rg < off){
          float4 aa = *(float4*)&lsum[rg*HD + c4], bb = *(float4*)&lsum[(rg+off)*HD + c4];
          aa.x+=bb.x; aa.y+=bb.y; aa.z+=bb.z; aa.w+=bb.w;
          *(float4*)&lsum[rg*HD + c4] = aa;
          float4 cc = *(float4*)&lsq[rg*HD + c4], ddv = *(float4*)&lsq[(rg+off)*HD + c4];
          cc.x+=ddv.x; cc.y+=ddv.y; cc.z+=ddv.z; cc.w+=ddv.w;
          *(float4*)&lsq[rg*HD + c4] = cc;
        }
        __syncthreads();
      }
      if (t < HD){
        atomicAdd(&sums[t],  lsum[t]);
        atomicAdd(&sumsq[t], lsq[t]);
      }
      __syncthreads();   // protect smem reuse across vb
    }
  }
  __threadfence(); gg.sync();

  // ---- P6: GEMM2 (MFMA f16, BN coef once per block in LDS) (1563 vb) ----
  {
    float* s_sc = (float*)smem;
    float* s_sh = s_sc + HD;
    if (t < HD){
      const float invN = 1.0f/(float)NN;
      float mu  = sums[t]*invN;
      float var = sumsq[t]*invN - mu*mu;
      float sc  = gamma[t]*rsqrtf(var+BN_EPS);
      s_sc[t] = sc;
      s_sh[t] = beta[t] - mu*sc;
    }
    __syncthreads();
    int w = t >> 6, l = t & 63;
    int kg = (l >> 4)*4;
    int oc = l & 15;
    for (int vb = blockIdx.x; vb < NB_GEMM; vb += NBLK){
      int arow = vb*64 + w*16 + (l & 15);
      const unsigned short* hr = hg + (size_t)min(arow, NN-1)*HD;
      f4v acc[4];
      #pragma unroll
      for (int i = 0; i < 4; ++i) acc[i] = (f4v){0.f,0.f,0.f,0.f};
      #pragma unroll
      for (int ks = 0; ks < 4; ++ks){
        uint2 u0 = *(const uint2*)&hr[ks*32 + kg];
        uint2 u1 = *(const uint2*)&hr[ks*32 + 16 + kg];
        float a00 = __uint_as_float(u0.x << 16), a01 = __uint_as_float(u0.x & 0xffff0000u);
        float a02 = __uint_as_float(u0.y << 16), a03 = __uint_as_float(u0.y & 0xffff0000u);
        float a10 = __uint_as_float(u1.x << 16), a11 = __uint_as_float(u1.x & 0xffff0000u);
        float a12 = __uint_as_float(u1.y << 16), a13 = __uint_as_float(u1.y & 0xffff0000u);
        float4 s0 = *(const float4*)&s_sc[ks*32 + kg];
        float4 s1 = *(const float4*)&s_sc[ks*32 + 16 + kg];
        float4 f0 = *(const float4*)&s_sh[ks*32 + kg];
        float4 f1 = *(const float4*)&s_sh[ks*32 + 16 + kg];
        h8 af;
        af[0]=(_Float16)fmaxf(a00*s0.x+f0.x,0.f);
        af[1]=(_Float16)fmaxf(a01*s0.y+f0.y,0.f);
        af[2]=(_Float16)fmaxf(a02*s0.z+f0.z,0.f);
        af[3]=(_Float16)fmaxf(a03*s0.w+f0.w,0.f);
        af[4]=(_Float16)fmaxf(a10*s1.x+f1.x,0.f);
        af[5]=(_Float16)fmaxf(a11*s1.y+f1.y,0.f);
        af[6]=(_Float16)fmaxf(a12*s1.z+f1.z,0.f);
        af[7]=(_Float16)fmaxf(a13*s1.w+f1.w,0.f);
        const unsigned short* wb = w2f + ((size_t)(ks*4)*64 + l)*8;
        #pragma unroll
        for (int nt = 0; nt < 4; ++nt){
          h8 bf = *(const h8*)(wb + (size_t)nt*64*8);
          acc[nt] = __builtin_amdgcn_mfma_f32_16x16x32_f16(af, bf, acc[nt], 0, 0, 0);
        }
      }
      int orow0 = vb*64 + w*16 + (l >> 4)*4;
      #pragma unroll
      for (int r = 0; r < 4; ++r){
        int rr = orow0 + r;
        if (rr < NN){
          float sc = dis[rr];
          #pragma unroll
          for (int nt = 0; nt < 4; ++nt)
            h2s[(size_t)rr*EM + nt*16 + oc] = bf16s(acc[nt][r]*sc);
        }
      }
    }
  }
  __threadfence(); gg.sync();

  // ---- P7: GCN2 gather (25000 vb) ----
  {
    int w = t >> 6, lane = t & 63;
    int sub = lane >> 4;
    int q = lane & 15;
    for (int vb = blockIdx.x; vb < NB_GATH; vb += NBLK){
      int d = vb*4 + w;
      float dd = dis[d];
      float4 a = make_float4(0.f,0.f,0.f,0.f);
      if (sub == 0){
        bfacc(a, *(const uint2*)&h2s[(size_t)d*EM + q*4]);   // self loop
      }
      int p0 = rowptr[d], p1 = rowptr[d+1];
      for (int base = p0; base < p1; base += 64){
        int idx = base + lane;
        int s_l = (idx < p1) ? esrc[idx] : 0;
        int m = min(64, p1 - base);
        int mm16 = m & ~15;
        for (int jb = 0; jb < mm16; jb += 16){
          int s0 = __shfl(s_l, jb + sub);
          int s1 = __shfl(s_l, jb + 4 + sub);
          int s2 = __shfl(s_l, jb + 8 + sub);
          int s3 = __shfl(s_l, jb + 12 + sub);
          uint2 v0 = *(const uint2*)&h2s[(size_t)s0*EM + q*4];
          uint2 v1 = *(const uint2*)&h2s[(size_t)s1*EM + q*4];
          uint2 v2 = *(const uint2*)&h2s[(size_t)s2*EM + q*4];
          uint2 v3 = *(const uint2*)&h2s[(size_t)s3*EM + q*4];
          bfacc(a, v0); bfacc(a, v1); bfacc(a, v2); bfacc(a, v3);
        }
        for (int j = mm16; j < m; j += 4){
          int jj = j + sub;
          int s = __shfl(s_l, min(jj, 63));
          if (jj < m){
            bfacc(a, *(const uint2*)&h2s[(size_t)s*EM + q*4]);
          }
        }
      }
      a.x += __shfl_xor(a.x, 32); a.y += __shfl_xor(a.y, 32);
      a.z += __shfl_xor(a.z, 32); a.w += __shfl_xor(a.w, 32);
      a.x += __shfl_xor(a.x, 16); a.y += __shfl_xor(a.y, 16);
      a.z += __shfl_xor(a.z, 16); a.w += __shfl_xor(a.w, 16);
      if (sub == 0){
        float4 b = *(const float4*)&b2v[q*4];
        a.x = a.x*dd + b.x; a.y = a.y*dd + b.y;
        a.z = a.z*dd + b.z; a.w = a.w*dd + b.w;
        *(float4*)&out[(size_t)d*EM + q*4] = a;   // emb block of out
      }
    }
  }
  __threadfence(); gg.sync();

  // ---- P8: logits (MFMA) + wave softmax (1563 vb) ----
  {
    int w = t >> 6, l = t & 63;
    int kg = (l >> 4)*4;
    int oc = l & 15;
    for (int vb = blockIdx.x; vb < NB_GEMM; vb += NBLK){
      int arow = vb*64 + w*16 + (l & 15);
      const float* er = out + (size_t)min(arow, NN-1)*EM;
      f4v acc[7];
      #pragma unroll
      for (int i = 0; i < 7; ++i) acc[i] = (f4v){0.f,0.f,0.f,0.f};
      #pragma unroll
      for (int ks = 0; ks < 2; ++ks){
        float4 a0 = *(const float4*)&er[ks*32 + kg];
        float4 a1 = *(const float4*)&er[ks*32 + 16 + kg];
        h8 af;
        af[0]=(_Float16)a0.x; af[1]=(_Float16)a0.y; af[2]=(_Float16)a0.z; af[3]=(_Float16)a0.w;
        af[4]=(_Float16)a1.x; af[5]=(_Float16)a1.y; af[6]=(_Float16)a1.z; af[7]=(_Float16)a1.w;
        const unsigned short* wb = cf + ((size_t)(ks*7)*64 + l)*8;
        #pragma unroll
        for (int nt = 0; nt < 7; ++nt){
          h8 bf = *(const h8*)(wb + (size_t)nt*64*8);
          acc[nt] = __builtin_amdgcn_mfma_f32_16x16x32_f16(af, bf, acc[nt], 0, 0, 0);
        }
      }
      int orow0 = vb*64 + w*16 + (l >> 4)*4;
      #pragma unroll
      for (int r = 0; r < 4; ++r){
        float lg[7];
        float mx = -1e30f;
        #pragma unroll
        for (int nt = 0; nt < 7; ++nt){
          int col = nt*16 + oc;
          lg[nt] = (col < KC) ? acc[nt][r] : -1e30f;
          mx = fmaxf(mx, lg[nt]);
        }
        #pragma unroll
        for (int off = 1; off <= 8; off <<= 1) mx = fmaxf(mx, __shfl_xor(mx, off));
        float ex[7];
        float ssum = 0.f;
        #pragma unroll
        for (int nt = 0; nt < 7; ++nt){
          int col = nt*16 + oc;
          ex[nt] = (col < KC) ? __expf(lg[nt] - mx) : 0.f;
          ssum += ex[nt];
        }
        #pragma unroll
        for (int off = 1; off <= 8; off <<= 1) ssum += __shfl_xor(ssum, off);
        float inv = 1.0f / ssum;
        int rr = orow0 + r;
        if (rr < NN){
          float* orow = out + (size_t)NN*EM + (size_t)rr*KC;
          #pragma unroll
          for (int nt = 0; nt < 7; ++nt){
            int col = nt*16 + oc;
            if (col < KC) orow[col] = ex[nt]*inv;
          }
        }
      }
    }
  }
}

// =================== fallback path: round-13 verified kernels ===============
__global__ __launch_bounds__(256) void k_part2(const int* __restrict__ ei,
                                               int* __restrict__ gcur,
                                               int2* __restrict__ pbuf){
  __shared__ int lh[NBK];
  __shared__ int lcur[NBK];
  int t = threadIdx.x;
  for (int i = t; i < NBK; i += 256) lh[i] = 0;
  __syncthreads();
  int e0 = blockIdx.x*2048;
  int se[8], de[8];
  #pragma unroll
  for (int i = 0; i < 8; ++i){
    int e = e0 + i*256 + t;
    if (e < EE){
      se[i] = ei[e]; de[i] = ei[EE + e];
      atomicAdd(&lh[de[i] >> 9], 1);
    }
  }
  __syncthreads();
  for (int i = t; i < NBK; i += 256)
    lcur[i] = lh[i] ? atomicAdd(&gcur[i], lh[i]) : 0;
  __syncthreads();
  #pragma unroll
  for (int i = 0; i < 8; ++i){
    int e = e0 + i*256 + t;
    if (e < EE){
      int b = de[i] >> 9;
      int pos = atomicAdd(&lcur[b], 1);
      pbuf[(size_t)b*BSTRIDE + pos] = make_int2(se[i], de[i]);
    }
  }
}

__global__ __launch_bounds__(256) void k_bfill2(const int2* __restrict__ pbuf,
                                                const int* __restrict__ gcur,
                                                int* __restrict__ rowptr,
                                                int* __restrict__ esrc,
                                                float* __restrict__ dis){
  __shared__ int lcnt[BKT];
  __shared__ int ls[256];
  __shared__ int sb[2];
  int b = blockIdx.x, t = threadIdx.x;
  int n0 = b*BKT;
  int v = (t < NBK) ? gcur[t] : 0;
  ls[t] = v; __syncthreads();
  #pragma unroll
  for (int off = 1; off < 256; off <<= 1){
    int x = (t >= off) ? ls[t-off] : 0;
    __syncthreads();
    ls[t] += x;
    __syncthreads();
  }
  if (t == b){ sb[0] = ls[t] - v; sb[1] = v; }
  if (b == 0 && t == 0) rowptr[NN] = EE;
  __syncthreads();
  int e0 = sb[0], cnt = sb[1];
  lcnt[2*t] = 0; lcnt[2*t+1] = 0;
  __syncthreads();
  const int2* pb = pbuf + (size_t)b*BSTRIDE;
  for (int e = t; e < cnt; e += 256)
    atomicAdd(&lcnt[pb[e].y - n0], 1);
  __syncthreads();
  int v0 = lcnt[2*t], v1 = lcnt[2*t+1];
  int s = v0 + v1;
  ls[t] = s; __syncthreads();
  #pragma unroll
  for (int off = 1; off < 256; off <<= 1){
    int x = (t >= off) ? ls[t-off] : 0;
    __syncthreads();
    ls[t] += x;
    __syncthreads();
  }
  int run = ls[t] - s;
  if (n0 + 2*t < NN){
    rowptr[n0 + 2*t] = e0 + run;
    dis[n0 + 2*t] = rsqrtf((float)v0 + 1.0f);
  }
  if (n0 + 2*t + 1 < NN){
    rowptr[n0 + 2*t + 1] = e0 + run + v0;
    dis[n0 + 2*t + 1] = rsqrtf((float)v1 + 1.0f);
  }
  lcnt[2*t] = run; lcnt[2*t+1] = run + v0;
  __syncthreads();
  for (int e = t; e < cnt; e += 256){
    int2 p = pb[e];
    int pos = atomicAdd(&lcnt[p.y - n0], 1);
    esrc[e0 + pos] = p.x;
  }
}

__global__ __launch_bounds__(256) void k_wprep_all(const float* __restrict__ W1,
                        const float* __restrict__ W2,
                        const float* __restrict__ ctr,
                        const float* __restrict__ temp,
                        unsigned short* __restrict__ w1f,
                        unsigned short* __restrict__ w2f,
                        unsigned short* __restrict__ cf,
                        int* __restrict__ gcur,
                        float* __restrict__ sums, float* __restrict__ sumsq){
  int b = blockIdx.x, t = threadIdx.x;
  if (b < 8){
    wprep_one(W1, HD, 8, w1f, b*256 + t);
    if (b == 0) gcur[t] = 0;
    if (b == 1 && t < HD){ sums[t] = 0.f; sumsq[t] = 0.f; }
  } else if (b < 12){
    wprep_one(W2, EM, 4, w2f, (b-8)*256 + t);
  } else {
    cprep_one(ctr, temp, cf, (b-12)*256 + t);
  }
}

__global__ __launch_bounds__(256) void k_gemm1(const float* __restrict__ x,
                                               const unsigned short* __restrict__ w1f,
                                               const float* __restrict__ dis,
                                               unsigned short* __restrict__ h1s){
  int t = threadIdx.x, w = t >> 6, l = t & 63;
  int arow = blockIdx.x*64 + w*16 + (l & 15);
  const float* xr = x + (size_t)min(arow, NN-1)*IND;
  int kg = (l >> 4)*4;
  f4v acc[8];
  #pragma unroll
  for (int i = 0; i < 8; ++i) acc[i] = (f4v){0.f,0.f,0.f,0.f};
  #pragma unroll
  for (int ks = 0; ks < 4; ++ks){
    float4 a0 = *(const float4*)&xr[ks*32 + kg];
    float4 a1 = *(const float4*)&xr[ks*32 + 16 + kg];
    h8 af;
    af[0]=(_Float16)a0.x; af[1]=(_Float16)a0.y; af[2]=(_Float16)a0.z; af[3]=(_Float16)a0.w;
    af[4]=(_Float16)a1.x; af[5]=(_Float16)a1.y; af[6]=(_Float16)a1.z; af[7]=(_Float16)a1.w;
    const unsigned short* wb = w1f + ((size_t)(ks*8)*64 + l)*8;
    #pragma unroll
    for (int nt = 0; nt < 8; ++nt){
      h8 bf = *(const h8*)(wb + (size_t)nt*64*8);
      acc[nt] = __builtin_amdgcn_mfma_f32_16x16x32_f16(af, bf, acc[nt], 0, 0, 0);
    }
  }
  int orow0 = blockIdx.x*64 + w*16 + (l >> 4)*4;
  int oc = l & 15;
  #pragma unroll
  for (int r = 0; r < 4; ++r){
    int rr = orow0 + r;
    if (rr < NN){
      float sc = dis[rr];
      #pragma unroll
      for (int nt = 0; nt < 8; ++nt)
        h1s[(size_t)rr*HD + nt*16 + oc] = bf16s(acc[nt][r]*sc);
    }
  }
}

__global__ __launch_bounds__(256) void k_gather1(
    const int* __restrict__ rowptr, const int* __restrict__ esrc,
    const float* __restrict__ dis, const unsigned short* __restrict__ h1s,
    const float* __restrict__ b1, unsigned short* __restrict__ hg){
  int w = threadIdx.x >> 6, lane = threadIdx.x & 63;
  int d = blockIdx.x*4 + w;
  int half = lane >> 5;
  int q = lane & 31;
  float dd = dis[d];
  float4 a = make_float4(0.f,0.f,0.f,0.f);
  if (half == 0){
    bfacc(a, *(const uint2*)&h1s[(size_t)d*HD + q*4]);
  }
  int p0 = rowptr[d], p1 = rowptr[d+1];
  for (int base = p0; base < p1; base += 64){
    int idx = base + lane;
    int s_l = (idx < p1) ? esrc[idx] : 0;
    int m = min(64, p1 - base);
    int mm8 = m & ~7;
    for (int jb = 0; jb < mm8; jb += 8){
      int s0 = __shfl(s_l, jb + half);
      int s1 = __shfl(s_l, jb + 2 + half);
      int s2 = __shfl(s_l, jb + 4 + half);
      int s3 = __shfl(s_l, jb + 6 + half);
      uint2 v0 = *(const uint2*)&h1s[(size_t)s0*HD + q*4];
      uint2 v1 = *(const uint2*)&h1s[(size_t)s1*HD + q*4];
      uint2 v2 = *(const uint2*)&h1s[(size_t)s2*HD + q*4];
      uint2 v3 = *(const uint2*)&h1s[(size_t)s3*HD + q*4];
      bfacc(a, v0); bfacc(a, v1); bfacc(a, v2); bfacc(a, v3);
    }
    for (int j = mm8; j < m; j += 2){
      int jj = j + half;
      int s = __shfl(s_l, jj);
      if (jj < m){
        bfacc(a, *(const uint2*)&h1s[(size_t)s*HD + q*4]);
      }
    }
  }
  a.x += __shfl_xor(a.x, 32); a.y += __shfl_xor(a.y, 32);
  a.z += __shfl_xor(a.z, 32); a.w += __shfl_xor(a.w, 32);
  if (half == 0){
    float4 b = *(const float4*)&b1[q*4];
    float vx = a.x*dd + b.x, vy = a.y*dd + b.y;
    float vz = a.z*dd + b.z, vw = a.w*dd + b.w;
    uint2 o; o.x = bf16pk(vx, vy); o.y = bf16pk(vz, vw);
    *(uint2*)&hg[(size_t)d*HD + q*4] = o;
  }
}

__global__ __launch_bounds__(256) void k_bn_stats(const unsigned short* __restrict__ hg,
                                                  float* __restrict__ sums,
                                                  float* __restrict__ sumsq){
  __shared__ float lsum[8][HD];
  __shared__ float lsq[8][HD];
  int t = threadIdx.x;
  int rg = t >> 5, c4 = (t & 31)*4;
  int r1 = min(blockIdx.x*BN2_ROWS + BN2_ROWS, NN);
  float4 s = make_float4(0.f,0.f,0.f,0.f), q = make_float4(0.f,0.f,0.f,0.f);
  for (int r = blockIdx.x*BN2_ROWS + rg; r < r1; r += 8){
    uint2 u = *(const uint2*)&hg[(size_t)r*HD + c4];
    float x0 = __uint_as_float(u.x << 16), x1 = __uint_as_float(u.x & 0xffff0000u);
    float x2 = __uint_as_float(u.y << 16), x3 = __uint_as_float(u.y & 0xffff0000u);
    s.x += x0; s.y += x1; s.z += x2; s.w += x3;
    q.x += x0*x0; q.y += x1*x1; q.z += x2*x2; q.w += x3*x3;
  }
  *(float4*)&lsum[rg][c4] = s;
  *(float4*)&lsq[rg][c4]  = q;
  __syncthreads();
  #pragma unroll
  for (int off = 4; off >= 1; off >>= 1){
    if (rg < off){
      float4 aa = *(float4*)&lsum[rg][c4], bb = *(float4*)&lsum[rg+off][c4];
      aa.x+=bb.x; aa.y+=bb.y; aa.z+=bb.z; aa.w+=bb.w;
      *(float4*)&lsum[rg][c4] = aa;
      float4 cc = *(float4*)&lsq[rg][c4], ddv = *(float4*)&lsq[rg+off][c4];
      cc.x+=ddv.x; cc.y+=ddv.y; cc.z+=ddv.z; cc.w+=ddv.w;
      *(float4*)&lsq[rg][c4] = cc;
    }
    __syncthreads();
  }
  if (t < HD){
    atomicAdd(&sums[t],  lsum[0][t]);
    atomicAdd(&sumsq[t], lsq[0][t]);
  }
}

__global__ __launch_bounds__(256) void k_gemm2(const unsigned short* __restrict__ hg,
                                               const unsigned short* __restrict__ w2f,
                                               const float* __restrict__ sums,
                                               const float* __restrict__ sumsq,
                                               const float* __restrict__ gamma,
                                               const float* __restrict__ beta,
                                               const float* __restrict__ dis,
                                               unsigned short* __restrict__ h2s){
  __shared__ float s_sc[HD];
  __shared__ float s_sh[HD];
  int t = threadIdx.x, w = t >> 6, l = t & 63;
  if (t < HD){
    const float invN = 1.0f/(float)NN;
    float mu  = sums[t]*invN;
    float var = sumsq[t]*invN - mu*mu;
    float sc  = gamma[t]*rsqrtf(var+BN_EPS);
    s_sc[t] = sc;
    s_sh[t] = beta[t] - mu*sc;
  }
  __syncthreads();
  int arow = blockIdx.x*64 + w*16 + (l & 15);
  const unsigned short* hr = hg + (size_t)min(arow, NN-1)*HD;
  int kg = (l >> 4)*4;
  f4v acc[4];
  #pragma unroll
  for (int i = 0; i < 4; ++i) acc[i] = (f4v){0.f,0.f,0.f,0.f};
  #pragma unroll
  for (int ks = 0; ks < 4; ++ks){
    uint2 u0 = *(const uint2*)&hr[ks*32 + kg];
    uint2 u1 = *(const uint2*)&hr[ks*32 + 16 + kg];
    float a00 = __uint_as_float(u0.x << 16), a01 = __uint_as_float(u0.x & 0xffff0000u);
    float a02 = __uint_as_float(u0.y << 16), a03 = __uint_as_float(u0.y & 0xffff0000u);
    float a10 = __uint_as_float(u1.x << 16), a11 = __uint_as_float(u1.x & 0xffff0000u);
    float a12 = __uint_as_float(u1.y << 16), a13 = __uint_as_float(u1.y & 0xffff0000u);
    float4 s0 = *(const float4*)&s_sc[ks*32 + kg];
    float4 s1 = *(const float4*)&s_sc[ks*32 + 16 + kg];
    float4 f0 = *(const float4*)&s_sh[ks*32 + kg];
    float4 f1 = *(const float4*)&s_sh[ks*32 + 16 + kg];
    h8 af;
    af[0]=(_Float16)fmaxf(a00*s0.x+f0.x,0.f);
    af[1]=(_Float16)fmaxf(a01*s0.y+f0.y,0.f);
    af[2]=(_Float16)fmaxf(a02*s0.z+f0.z,0.f);
    af[3]=(_Float16)fmaxf(a03*s0.w+f0.w,0.f);
    af[4]=(_Float16)fmaxf(a10*s1.x+f1.x,0.f);
    af[5]=(_Float16)fmaxf(a11*s1.y+f1.y,0.f);
    af[6]=(_Float16)fmaxf(a12*s1.z+f1.z,0.f);
    af[7]=(_Float16)fmaxf(a13*s1.w+f1.w,0.f);
    const unsigned short* wb = w2f + ((size_t)(ks*4)*64 + l)*8;
    #pragma unroll
    for (int nt = 0; nt < 4; ++nt){
      h8 bf = *(const h8*)(wb + (size_t)nt*64*8);
      acc[nt] = __builtin_amdgcn_mfma_f32_16x16x32_f16(af, bf, acc[nt], 0, 0, 0);
    }
  }
  int orow0 = blockIdx.x*64 + w*16 + (l >> 4)*4;
  int oc = l & 15;
  #pragma unroll
  for (int r = 0; r < 4; ++r){
    int rr = orow0 + r;
    if (rr < NN){
      float sc = dis[rr];
      #pragma unroll
      for (int nt = 0; nt < 4; ++nt)
        h2s[(size_t)rr*EM + nt*16 + oc] = bf16s(acc[nt][r]*sc);
    }
  }
}

__global__ __launch_bounds__(256) void k_gather2(
    const int* __restrict__ rowptr, const int* __restrict__ esrc,
    const float* __restrict__ dis, const unsigned short* __restrict__ h2s,
    const float* __restrict__ b2v, float* __restrict__ out){
  int w = threadIdx.x >> 6, lane = threadIdx.x & 63;
  int d = blockIdx.x*4 + w;
  int sub = lane >> 4;
  int q = lane & 15;
  float dd = dis[d];
  float4 a = make_float4(0.f,0.f,0.f,0.f);
  if (sub == 0){
    bfacc(a, *(const uint2*)&h2s[(size_t)d*EM + q*4]);
  }
  int p0 = rowptr[d], p1 = rowptr[d+1];
  for (int base = p0; base < p1; base += 64){
    int idx = base + lane;
    int s_l = (idx < p1) ? esrc[idx] : 0;
    int m = min(64, p1 - base);
    int mm16 = m & ~15;
    for (int jb = 0; jb < mm16; jb += 16){
      int s0 = __shfl(s_l, jb + sub);
      int s1 = __shfl(s_l, jb + 4 + sub);
      int s2 = __shfl(s_l, jb + 8 + sub);
      int s3 = __shfl(s_l, jb + 12 + sub);
      uint2 v0 = *(const uint2*)&h2s[(size_t)s0*EM + q*4];
      uint2 v1 = *(const uint2*)&h2s[(size_t)s1*EM + q*4];
      uint2 v2 = *(const uint2*)&h2s[(size_t)s2*EM + q*4];
      uint2 v3 = *(const uint2*)&h2s[(size_t)s3*EM + q*4];
      bfacc(a, v0); bfacc(a, v1); bfacc(a, v2); bfacc(a, v3);
    }
    for (int j = mm16; j < m; j += 4){
      int jj = j + sub;
      int s = __shfl(s_l, min(jj, 63));
      if (jj < m){
        bfacc(a, *(const uint2*)&h2s[(size_t)s*EM + q*4]);
      }
    }
  }
  a.x += __shfl_xor(a.x, 32); a.y += __shfl_xor(a.y, 32);
  a.z += __shfl_xor(a.z, 32); a.w += __shfl_xor(a.w, 32);
  a.x += __shfl_xor(a.x, 16); a.y += __shfl_xor(a.y, 16);
  a.z += __shfl_xor(a.z, 16); a.w += __shfl_xor(a.w, 16);
  if (sub == 0){
    float4 b = *(const float4*)&b2v[q*4];
    a.x = a.x*dd + b.x; a.y = a.y*dd + b.y;
    a.z = a.z*dd + b.z; a.w = a.w*dd + b.w;
    *(float4*)&out[(size_t)d*EM + q*4] = a;
  }
}

__global__ __launch_bounds__(256) void k_softmax(const float* __restrict__ embf,
                          const unsigned short* __restrict__ cf,
                          float* __restrict__ out){
  int t = threadIdx.x, w = t >> 6, l = t & 63;
  int arow = blockIdx.x*64 + w*16 + (l & 15);
  const float* er = embf + (size_t)min(arow, NN-1)*EM;
  int kg = (l >> 4)*4;
  f4v acc[7];
  #pragma unroll
  for (int i = 0; i < 7; ++i) acc[i] = (f4v){0.f,0.f,0.f,0.f};
  #pragma unroll
  for (int ks = 0; ks < 2; ++ks){
    float4 a0 = *(const float4*)&er[ks*32 + kg];
    float4 a1 = *(const float4*)&er[ks*32 + 16 + kg];
    h8 af;
    af[0]=(_Float16)a0.x; af[1]=(_Float16)a0.y; af[2]=(_Float16)a0.z; af[3]=(_Float16)a0.w;
    af[4]=(_Float16)a1.x; af[5]=(_Float16)a1.y; af[6]=(_Float16)a1.z; af[7]=(_Float16)a1.w;
    const unsigned short* wb = cf + ((size_t)(ks*7)*64 + l)*8;
    #pragma unroll
    for (int nt = 0; nt < 7; ++nt){
      h8 bf = *(const h8*)(wb + (size_t)nt*64*8);
      acc[nt] = __builtin_amdgcn_mfma_f32_16x16x32_f16(af, bf, acc[nt], 0, 0, 0);
    }
  }
  int orow0 = blockIdx.x*64 + w*16 + (l >> 4)*4;
  int oc = l & 15;
  #pragma unroll
  for (int r = 0; r < 4; ++r){
    float lg[7];
    float mx = -1e30f;
    #pragma unroll
    for (int nt = 0; nt < 7; ++nt){
      int col = nt*16 + oc;
      lg[nt] = (col < KC) ? acc[nt][r] : -1e30f;
      mx = fmaxf(mx, lg[nt]);
    }
    #pragma unroll
    for (int off = 1; off <= 8; off <<= 1) mx = fmaxf(mx, __shfl_xor(mx, off));
    float ex[7];
    float ssum = 0.f;
    #pragma unroll
    for (int nt = 0; nt < 7; ++nt){
      int col = nt*16 + oc;
      ex[nt] = (col < KC) ? __expf(lg[nt] - mx) : 0.f;
      ssum += ex[nt];
    }
    #pragma unroll
    for (int off = 1; off <= 8; off <<= 1) ssum += __shfl_xor(ssum, off);
    float inv = 1.0f / ssum;
    int rr = orow0 + r;
    if (rr < NN){
      float* orow = out + (size_t)NN*EM + (size_t)rr*KC;
      #pragma unroll
      for (int nt = 0; nt < 7; ++nt){
        int col = nt*16 + oc;
        if (col < KC) orow[col] = ex[nt]*inv;
      }
    }
  }
}

// ---------------- launch ----------------
extern "C" void kernel_launch(void* const* d_in, const int* in_sizes, int n_in,
                              void* d_out, int out_size, void* d_ws, size_t ws_size,
                              hipStream_t stream){
  const float* x      = (const float*)d_in[0];
  const int*   ei     = (const int*)d_in[1];
  const float* W1     = (const float*)d_in[2];
  const float* b1     = (const float*)d_in[3];
  const float* gamma  = (const float*)d_in[4];
  const float* beta   = (const float*)d_in[5];
  const float* W2     = (const float*)d_in[6];
  const float* b2v    = (const float*)d_in[7];
  const float* ctr    = (const float*)d_in[8];
  const float* temp   = (const float*)d_in[9];
  float* out = (float*)d_out;

  float* ws     = (float*)d_ws;
  float* dis    = ws;
  float* bufA   = dis + NN;
  float* bufB   = bufA + (size_t)NN*HD;
  float* sums   = bufB + (size_t)NN*HD;
  float* sumsq  = sums + HD;
  int*   rowptr = (int*)(sumsq + HD);
  int*   esrc   = rowptr + NN + 1;
  int*   gcur   = esrc + EE;
  unsigned short* w1f = (unsigned short*)(((uintptr_t)(gcur + 256) + 15) & ~(uintptr_t)15);
  unsigned short* w2f = w1f + 4*8*64*8;
  unsigned short* cf  = w2f + 4*4*64*8;
  int2*  pbuf   = (int2*)bufB;

  unsigned short* h1s = (unsigned short*)bufA;
  unsigned short* hg  = (unsigned short*)bufB;
  unsigned short* h2s = (unsigned short*)bufA;

  // ---- preferred: single cooperative mega-kernel ----
  bool done = false;
  int maxb = 0;
  if (hipOccupancyMaxActiveBlocksPerMultiprocessor(&maxb, (const void*)k_mega, 256, 0)
        == hipSuccess && maxb > 0){
    int gblks = maxb * 256;          // 256 CUs on MI355X
    if (gblks > 2048) gblks = 2048;
    void* args[] = { (void*)&x, (void*)&ei, (void*)&W1, (void*)&b1, (void*)&gamma,
                     (void*)&beta, (void*)&W2, (void*)&b2v, (void*)&ctr, (void*)&temp,
                     (void*)&dis, (void*)&rowptr, (void*)&esrc, (void*)&gcur,
                     (void*)&w1f, (void*)&w2f, (void*)&cf, (void*)&pbuf,
                     (void*)&h1s, (void*)&hg, (void*)&h2s, (void*)&sums,
                     (void*)&sumsq, (void*)&out };
    done = (hipLaunchCooperativeKernel((const void*)k_mega, dim3(gblks), dim3(256),
                                       args, 0, stream) == hipSuccess);
  }

  if (!done){
    // ---- fallback: round-13 verified 9-kernel path ----
    k_wprep_all<<<16, 256, 0, stream>>>(W1, W2, ctr, temp, w1f, w2f, cf, gcur, sums, sumsq);
    k_part2  <<<NB_PART, 256, 0, stream>>>(ei, gcur, pbuf);
    k_bfill2 <<<NBK, 256, 0, stream>>>(pbuf, gcur, rowptr, esrc, dis);
    k_gemm1  <<<NB_GEMM, 256, 0, stream>>>(x, w1f, dis, h1s);
    k_gather1<<<NB_GATH, 256, 0, stream>>>(rowptr, esrc, dis, h1s, b1, hg);
    k_bn_stats<<<NB_BN, 256, 0, stream>>>(hg, sums, sumsq);
    k_gemm2  <<<NB_GEMM, 256, 0, stream>>>(hg, w2f, sums, sumsq, gamma, beta, dis, h2s);
    k_gather2<<<NB_GATH, 256, 0, stream>>>(rowptr, esrc, dis, h2s, b2v, out);
    k_softmax<<<NB_GEMM, 256, 0, stream>>>(out, cf, out);
  }
}

// Round 15
// 352.168 us; speedup vs baseline: 4.0188x; 4.0188x over previous
//
#include <hip/hip_runtime.h>
#include <hip/hip_bf16.h>
#include <stdint.h>

#define NN 100000
#define EE 1600000
#define IND 128
#define HD 128
#define EM 64
#define KC 100
#define BN_EPS 1e-5f
#define BKT 512
#define NBK ((NN + BKT - 1) / BKT)      // 196 buckets (dst >> 9)
#define BSTRIDE 16384                    // slots per bucket in pbuf (mean 8192, ~90 sigma safe)
#define BN2_ROWS 256

typedef _Float16 h8 __attribute__((ext_vector_type(8)));
typedef float f4v __attribute__((ext_vector_type(4)));

// bf16 helpers: low short = first element
__device__ __forceinline__ unsigned bf16pk(float lo, float hi){
  unsigned a = __float_as_uint(lo), b = __float_as_uint(hi);
  a += 0x7fffu + ((a >> 16) & 1u);
  b += 0x7fffu + ((b >> 16) & 1u);
  return (a >> 16) | (b & 0xffff0000u);
}
__device__ __forceinline__ unsigned short bf16s(float v){
  unsigned u = __float_as_uint(v);
  u += 0x7fffu + ((u >> 16) & 1u);
  return (unsigned short)(u >> 16);
}
__device__ __forceinline__ void bfacc(float4& a, uint2 v){
  a.x += __uint_as_float(v.x << 16);
  a.y += __uint_as_float(v.x & 0xffff0000u);
  a.z += __uint_as_float(v.y << 16);
  a.w += __uint_as_float(v.y & 0xffff0000u);
}

// ---- CSR build, pass 1: edges->registers, LDS hist, relative reservation,
// scatter into fixed-stride bucket regions. No prior scan needed. ----------
__global__ __launch_bounds__(256) void k_part2(const int* __restrict__ ei,
                                               int* __restrict__ gcur,
                                               int2* __restrict__ pbuf){
  __shared__ int lh[NBK];
  __shared__ int lcur[NBK];
  int t = threadIdx.x;
  for (int i = t; i < NBK; i += 256) lh[i] = 0;
  __syncthreads();
  int e0 = blockIdx.x*2048;
  int se[8], de[8];
  #pragma unroll
  for (int i = 0; i < 8; ++i){
    int e = e0 + i*256 + t;
    if (e < EE){
      se[i] = ei[e]; de[i] = ei[EE + e];
      atomicAdd(&lh[de[i] >> 9], 1);
    }
  }
  __syncthreads();
  for (int i = t; i < NBK; i += 256)
    lcur[i] = lh[i] ? atomicAdd(&gcur[i], lh[i]) : 0;   // gcur starts at 0
  __syncthreads();
  #pragma unroll
  for (int i = 0; i < 8; ++i){
    int e = e0 + i*256 + t;
    if (e < EE){
      int b = de[i] >> 9;
      int pos = atomicAdd(&lcur[b], 1);
      pbuf[(size_t)b*BSTRIDE + pos] = make_int2(se[i], de[i]);
    }
  }
}

// ---- CSR build, pass 2: per-bucket. Redundant 196-entry global scan per
// block (cheap), then node hist + local scan + cursor fill as before. ------
__global__ __launch_bounds__(256) void k_bfill2(const int2* __restrict__ pbuf,
                                                const int* __restrict__ gcur,
                                                int* __restrict__ rowptr,
                                                int* __restrict__ esrc,
                                                float* __restrict__ dis){
  __shared__ int lcnt[BKT];
  __shared__ int ls[256];
  __shared__ int sb[2];
  int b = blockIdx.x, t = threadIdx.x;
  int n0 = b*BKT;
  // global exclusive scan of bucket counts
  int v = (t < NBK) ? gcur[t] : 0;
  ls[t] = v; __syncthreads();
  #pragma unroll
  for (int off = 1; off < 256; off <<= 1){
    int x = (t >= off) ? ls[t-off] : 0;
    __syncthreads();
    ls[t] += x;
    __syncthreads();
  }
  if (t == b){ sb[0] = ls[t] - v; sb[1] = v; }   // e0 (exclusive), count
  if (b == 0 && t == 0) rowptr[NN] = EE;
  __syncthreads();
  int e0 = sb[0], cnt = sb[1];
  // per-node hist
  lcnt[2*t] = 0; lcnt[2*t+1] = 0;
  __syncthreads();
  const int2* pb = pbuf + (size_t)b*BSTRIDE;
  for (int e = t; e < cnt; e += 256)
    atomicAdd(&lcnt[pb[e].y - n0], 1);
  __syncthreads();
  int v0 = lcnt[2*t], v1 = lcnt[2*t+1];
  int s = v0 + v1;
  ls[t] = s; __syncthreads();
  #pragma unroll
  for (int off = 1; off < 256; off <<= 1){
    int x = (t >= off) ? ls[t-off] : 0;
    __syncthreads();
    ls[t] += x;
    __syncthreads();
  }
  int run = ls[t] - s;                    // exclusive prefix (pairs)
  if (n0 + 2*t < NN){
    rowptr[n0 + 2*t] = e0 + run;
    dis[n0 + 2*t] = rsqrtf((float)v0 + 1.0f);
  }
  if (n0 + 2*t + 1 < NN){
    rowptr[n0 + 2*t + 1] = e0 + run + v0;
    dis[n0 + 2*t + 1] = rsqrtf((float)v1 + 1.0f);
  }
  lcnt[2*t] = run; lcnt[2*t+1] = run + v0;  // relative cursors
  __syncthreads();
  for (int e = t; e < cnt; e += 256){
    int2 p = pb[e];
    int pos = atomicAdd(&lcnt[p.y - n0], 1);
    esrc[e0 + pos] = p.x;
  }
}

// -------- W fragment prep (fused with gcur/sums zeroing + centers prep) -----
// entry = (ks*nt_cnt + nt)*64 + lane; elem j: k = ks*32 + (j>>2)*16 + (lane>>4)*4 + (j&3)
// n = nt*16 + (lane&15).  The SAME k-formula is used for A-frag loads in the
// GEMMs, so any deviation from the HW's true k-map cancels (bijective-k trick).
__device__ __forceinline__ void wprep_one(const float* __restrict__ W, int N, int nt_cnt,
                                          unsigned short* __restrict__ wf, int e){
  int total = 4*nt_cnt*64;
  if (e >= total) return;
  int lane = e & 63;
  int nt = (e >> 6) % nt_cnt;
  int ks = (e >> 6) / nt_cnt;
  int n = nt*16 + (lane & 15);
  int kb = ks*32 + (lane >> 4)*4;
  unsigned short out[8];
  #pragma unroll
  for (int j = 0; j < 8; ++j){
    int k = kb + (j>>2)*16 + (j&3);
    _Float16 h = (_Float16)W[k*N + n];
    out[j] = *(unsigned short*)&h;
  }
  *(uint4*)&wf[(size_t)e*8] = *(const uint4*)out;
}

__global__ __launch_bounds__(256) void k_wprep_all(const float* __restrict__ W1,
                        const float* __restrict__ W2,
                        const float* __restrict__ ctr,
                        const float* __restrict__ temp,
                        unsigned short* __restrict__ w1f,
                        unsigned short* __restrict__ w2f,
                        unsigned short* __restrict__ cf,
                        int* __restrict__ gcur,
                        float* __restrict__ sums, float* __restrict__ sumsq){
  int b = blockIdx.x, t = threadIdx.x;
  if (b < 8){
    wprep_one(W1, HD, 8, w1f, b*256 + t);
    if (b == 0) gcur[t] = 0;
    if (b == 1 && t < HD){ sums[t] = 0.f; sumsq[t] = 0.f; }
  } else if (b < 12){
    wprep_one(W2, EM, 4, w2f, (b-8)*256 + t);
  } else {
    // centers B-frags: B[k][n] = centers[n][k] * (1/T); ks_cnt=2, nt_cnt=7,
    // n>=KC padded with 0 (masked in softmax epilogue).
    int e = (b-12)*256 + t;
    int total = 2*7*64;
    if (e < total){
      float invT = 1.0f / temp[0];
      int lane = e & 63;
      int nt = (e >> 6) % 7;
      int ks = (e >> 6) / 7;
      int n = nt*16 + (lane & 15);
      int kb = ks*32 + (lane >> 4)*4;
      unsigned short o[8];
      #pragma unroll
      for (int j = 0; j < 8; ++j){
        int k = kb + (j>>2)*16 + (j&3);
        float v = (n < KC) ? ctr[n*EM + k]*invT : 0.f;
        _Float16 h = (_Float16)v;
        o[j] = *(unsigned short*)&h;
      }
      *(uint4*)&cf[(size_t)e*8] = *(const uint4*)o;
    }
  }
}

// ------- GEMM1 (MFMA f16): h1s = bf16( (x @ W1) * dis[row] ) ----------------
__global__ __launch_bounds__(256) void k_gemm1(const float* __restrict__ x,
                                               const unsigned short* __restrict__ w1f,
                                               const float* __restrict__ dis,
                                               unsigned short* __restrict__ h1s){
  int t = threadIdx.x, w = t >> 6, l = t & 63;
  int arow = blockIdx.x*64 + w*16 + (l & 15);
  const float* xr = x + (size_t)min(arow, NN-1)*IND;
  int kg = (l >> 4)*4;
  f4v acc[8];
  #pragma unroll
  for (int i = 0; i < 8; ++i) acc[i] = (f4v){0.f,0.f,0.f,0.f};
  #pragma unroll
  for (int ks = 0; ks < 4; ++ks){
    float4 a0 = *(const float4*)&xr[ks*32 + kg];
    float4 a1 = *(const float4*)&xr[ks*32 + 16 + kg];
    h8 af;
    af[0]=(_Float16)a0.x; af[1]=(_Float16)a0.y; af[2]=(_Float16)a0.z; af[3]=(_Float16)a0.w;
    af[4]=(_Float16)a1.x; af[5]=(_Float16)a1.y; af[6]=(_Float16)a1.z; af[7]=(_Float16)a1.w;
    const unsigned short* wb = w1f + ((size_t)(ks*8)*64 + l)*8;
    #pragma unroll
    for (int nt = 0; nt < 8; ++nt){
      h8 bf = *(const h8*)(wb + (size_t)nt*64*8);
      acc[nt] = __builtin_amdgcn_mfma_f32_16x16x32_f16(af, bf, acc[nt], 0, 0, 0);
    }
  }
  int orow0 = blockIdx.x*64 + w*16 + (l >> 4)*4;
  int oc = l & 15;
  #pragma unroll
  for (int r = 0; r < 4; ++r){
    int rr = orow0 + r;
    if (rr < NN){
      float sc = dis[rr];
      #pragma unroll
      for (int nt = 0; nt < 8; ++nt)
        h1s[(size_t)rr*HD + nt*16 + oc] = bf16s(acc[nt][r]*sc);
    }
  }
}

// ---- GCN1 gather: 1 wave/node, bf16 rows (256 B); hg output is bf16 --------
__global__ __launch_bounds__(256) void k_gather1(
    const int* __restrict__ rowptr, const int* __restrict__ esrc,
    const float* __restrict__ dis, const unsigned short* __restrict__ h1s,
    const float* __restrict__ b1, unsigned short* __restrict__ hg){
  int w = threadIdx.x >> 6, lane = threadIdx.x & 63;
  int d = blockIdx.x*4 + w;
  int half = lane >> 5;
  int q = lane & 31;
  float dd = dis[d];
  float4 a = make_float4(0.f,0.f,0.f,0.f);
  if (half == 0){
    bfacc(a, *(const uint2*)&h1s[(size_t)d*HD + q*4]);   // self loop
  }
  int p0 = rowptr[d], p1 = rowptr[d+1];
  for (int base = p0; base < p1; base += 64){
    int idx = base + lane;
    int s_l = (idx < p1) ? esrc[idx] : 0;   // coalesced: 64 edge indices
    int m = min(64, p1 - base);             // wave-uniform
    int mm8 = m & ~7;
    for (int jb = 0; jb < mm8; jb += 8){
      int s0 = __shfl(s_l, jb + half);
      int s1 = __shfl(s_l, jb + 2 + half);
      int s2 = __shfl(s_l, jb + 4 + half);
      int s3 = __shfl(s_l, jb + 6 + half);
      uint2 v0 = *(const uint2*)&h1s[(size_t)s0*HD + q*4];
      uint2 v1 = *(const uint2*)&h1s[(size_t)s1*HD + q*4];
      uint2 v2 = *(const uint2*)&h1s[(size_t)s2*HD + q*4];
      uint2 v3 = *(const uint2*)&h1s[(size_t)s3*HD + q*4];
      bfacc(a, v0); bfacc(a, v1); bfacc(a, v2); bfacc(a, v3);
    }
    for (int j = mm8; j < m; j += 2){
      int jj = j + half;                    // jj <= m <= 63 here
      int s = __shfl(s_l, jj);
      if (jj < m){
        bfacc(a, *(const uint2*)&h1s[(size_t)s*HD + q*4]);
      }
    }
  }
  a.x += __shfl_xor(a.x, 32); a.y += __shfl_xor(a.y, 32);
  a.z += __shfl_xor(a.z, 32); a.w += __shfl_xor(a.w, 32);
  if (half == 0){
    float4 b = *(const float4*)&b1[q*4];
    float vx = a.x*dd + b.x, vy = a.y*dd + b.y;
    float vz = a.z*dd + b.z, vw = a.w*dd + b.w;
    uint2 o; o.x = bf16pk(vx, vy); o.y = bf16pk(vz, vw);
    *(uint2*)&hg[(size_t)d*HD + q*4] = o;
  }
}

// ---- BatchNorm stats over bf16 hg: uint2 loads, 8 row-groups x 32 cols ----
__global__ __launch_bounds__(256) void k_bn_stats(const unsigned short* __restrict__ hg,
                                                  float* __restrict__ sums,
                                                  float* __restrict__ sumsq){
  __shared__ float lsum[8][HD];
  __shared__ float lsq[8][HD];
  int t = threadIdx.x;
  int rg = t >> 5, c4 = (t & 31)*4;
  int r1 = min(blockIdx.x*BN2_ROWS + BN2_ROWS, NN);
  float4 s = make_float4(0.f,0.f,0.f,0.f), q = make_float4(0.f,0.f,0.f,0.f);
  for (int r = blockIdx.x*BN2_ROWS + rg; r < r1; r += 8){
    uint2 u = *(const uint2*)&hg[(size_t)r*HD + c4];
    float x0 = __uint_as_float(u.x << 16), x1 = __uint_as_float(u.x & 0xffff0000u);
    float x2 = __uint_as_float(u.y << 16), x3 = __uint_as_float(u.y & 0xffff0000u);
    s.x += x0; s.y += x1; s.z += x2; s.w += x3;
    q.x += x0*x0; q.y += x1*x1; q.z += x2*x2; q.w += x3*x3;
  }
  *(float4*)&lsum[rg][c4] = s;
  *(float4*)&lsq[rg][c4]  = q;
  __syncthreads();
  #pragma unroll
  for (int off = 4; off >= 1; off >>= 1){
    if (rg < off){
      float4 aa = *(float4*)&lsum[rg][c4], bb = *(float4*)&lsum[rg+off][c4];
      aa.x+=bb.x; aa.y+=bb.y; aa.z+=bb.z; aa.w+=bb.w;
      *(float4*)&lsum[rg][c4] = aa;
      float4 cc = *(float4*)&lsq[rg][c4], ddv = *(float4*)&lsq[rg+off][c4];
      cc.x+=ddv.x; cc.y+=ddv.y; cc.z+=ddv.z; cc.w+=ddv.w;
      *(float4*)&lsq[rg][c4] = cc;
    }
    __syncthreads();
  }
  if (t < HD){
    atomicAdd(&sums[t],  lsum[0][t]);
    atomicAdd(&sumsq[t], lsq[0][t]);
  }
}

// ------- GEMM2 (MFMA f16, bf16 A-input, BN coef per-block in LDS) -----------
__global__ __launch_bounds__(256) void k_gemm2(const unsigned short* __restrict__ hg,
                                               const unsigned short* __restrict__ w2f,
                                               const float* __restrict__ sums,
                                               const float* __restrict__ sumsq,
                                               const float* __restrict__ gamma,
                                               const float* __restrict__ beta,
                                               const float* __restrict__ dis,
                                               unsigned short* __restrict__ h2s){
  __shared__ float s_sc[HD];
  __shared__ float s_sh[HD];
  int t = threadIdx.x, w = t >> 6, l = t & 63;
  if (t < HD){
    const float invN = 1.0f/(float)NN;
    float mu  = sums[t]*invN;
    float var = sumsq[t]*invN - mu*mu;
    float sc  = gamma[t]*rsqrtf(var+BN_EPS);
    s_sc[t] = sc;
    s_sh[t] = beta[t] - mu*sc;
  }
  __syncthreads();
  int arow = blockIdx.x*64 + w*16 + (l & 15);
  const unsigned short* hr = hg + (size_t)min(arow, NN-1)*HD;
  int kg = (l >> 4)*4;
  f4v acc[4];
  #pragma unroll
  for (int i = 0; i < 4; ++i) acc[i] = (f4v){0.f,0.f,0.f,0.f};
  #pragma unroll
  for (int ks = 0; ks < 4; ++ks){
    uint2 u0 = *(const uint2*)&hr[ks*32 + kg];
    uint2 u1 = *(const uint2*)&hr[ks*32 + 16 + kg];
    float a00 = __uint_as_float(u0.x << 16), a01 = __uint_as_float(u0.x & 0xffff0000u);
    float a02 = __uint_as_float(u0.y << 16), a03 = __uint_as_float(u0.y & 0xffff0000u);
    float a10 = __uint_as_float(u1.x << 16), a11 = __uint_as_float(u1.x & 0xffff0000u);
    float a12 = __uint_as_float(u1.y << 16), a13 = __uint_as_float(u1.y & 0xffff0000u);
    float4 s0 = *(const float4*)&s_sc[ks*32 + kg];
    float4 s1 = *(const float4*)&s_sc[ks*32 + 16 + kg];
    float4 f0 = *(const float4*)&s_sh[ks*32 + kg];
    float4 f1 = *(const float4*)&s_sh[ks*32 + 16 + kg];
    h8 af;
    af[0]=(_Float16)fmaxf(a00*s0.x+f0.x,0.f);
    af[1]=(_Float16)fmaxf(a01*s0.y+f0.y,0.f);
    af[2]=(_Float16)fmaxf(a02*s0.z+f0.z,0.f);
    af[3]=(_Float16)fmaxf(a03*s0.w+f0.w,0.f);
    af[4]=(_Float16)fmaxf(a10*s1.x+f1.x,0.f);
    af[5]=(_Float16)fmaxf(a11*s1.y+f1.y,0.f);
    af[6]=(_Float16)fmaxf(a12*s1.z+f1.z,0.f);
    af[7]=(_Float16)fmaxf(a13*s1.w+f1.w,0.f);
    const unsigned short* wb = w2f + ((size_t)(ks*4)*64 + l)*8;
    #pragma unroll
    for (int nt = 0; nt < 4; ++nt){
      h8 bf = *(const h8*)(wb + (size_t)nt*64*8);
      acc[nt] = __builtin_amdgcn_mfma_f32_16x16x32_f16(af, bf, acc[nt], 0, 0, 0);
    }
  }
  int orow0 = blockIdx.x*64 + w*16 + (l >> 4)*4;
  int oc = l & 15;
  #pragma unroll
  for (int r = 0; r < 4; ++r){
    int rr = orow0 + r;
    if (rr < NN){
      float sc = dis[rr];
      #pragma unroll
      for (int nt = 0; nt < 4; ++nt)
        h2s[(size_t)rr*EM + nt*16 + oc] = bf16s(acc[nt][r]*sc);
    }
  }
}

// -- GCN2 gather: bf16 rows (128 B), 4 subs of 16 lanes, uniform shfl --------
__global__ __launch_bounds__(256) void k_gather2(
    const int* __restrict__ rowptr, const int* __restrict__ esrc,
    const float* __restrict__ dis, const unsigned short* __restrict__ h2s,
    const float* __restrict__ b2v, float* __restrict__ out){
  int w = threadIdx.x >> 6, lane = threadIdx.x & 63;
  int d = blockIdx.x*4 + w;
  int sub = lane >> 4;
  int q = lane & 15;
  float dd = dis[d];
  float4 a = make_float4(0.f,0.f,0.f,0.f);
  if (sub == 0){
    bfacc(a, *(const uint2*)&h2s[(size_t)d*EM + q*4]);   // self loop
  }
  int p0 = rowptr[d], p1 = rowptr[d+1];
  for (int base = p0; base < p1; base += 64){
    int idx = base + lane;
    int s_l = (idx < p1) ? esrc[idx] : 0;
    int m = min(64, p1 - base);             // wave-uniform
    int mm16 = m & ~15;
    for (int jb = 0; jb < mm16; jb += 16){
      int s0 = __shfl(s_l, jb + sub);
      int s1 = __shfl(s_l, jb + 4 + sub);
      int s2 = __shfl(s_l, jb + 8 + sub);
      int s3 = __shfl(s_l, jb + 12 + sub);
      uint2 v0 = *(const uint2*)&h2s[(size_t)s0*EM + q*4];
      uint2 v1 = *(const uint2*)&h2s[(size_t)s1*EM + q*4];
      uint2 v2 = *(const uint2*)&h2s[(size_t)s2*EM + q*4];
      uint2 v3 = *(const uint2*)&h2s[(size_t)s3*EM + q*4];
      bfacc(a, v0); bfacc(a, v1); bfacc(a, v2); bfacc(a, v3);
    }
    for (int j = mm16; j < m; j += 4){
      int jj = j + sub;
      int s = __shfl(s_l, min(jj, 63));
      if (jj < m){
        bfacc(a, *(const uint2*)&h2s[(size_t)s*EM + q*4]);
      }
    }
  }
  a.x += __shfl_xor(a.x, 32); a.y += __shfl_xor(a.y, 32);
  a.z += __shfl_xor(a.z, 32); a.w += __shfl_xor(a.w, 32);
  a.x += __shfl_xor(a.x, 16); a.y += __shfl_xor(a.y, 16);
  a.z += __shfl_xor(a.z, 16); a.w += __shfl_xor(a.w, 16);
  if (sub == 0){
    float4 b = *(const float4*)&b2v[q*4];
    a.x = a.x*dd + b.x; a.y = a.y*dd + b.y;
    a.z = a.z*dd + b.z; a.w = a.w*dd + b.w;
    *(float4*)&out[(size_t)d*EM + q*4] = a;   // emb block of out (softmax reads)
  }
}

// ---- logits (MFMA f16, N=112 padded) + wave softmax -------------------------
// C/D map (HW-verified): row = orow0 + (l>>4)*4 + r, col = nt*16 + (l&15).
// Each 16-lane group owns 4 rows; row reductions are shfl_xor(1,2,4,8),
// group-local and wave-uniform.
__global__ __launch_bounds__(256) void k_softmax(const float* __restrict__ embf,
                          const unsigned short* __restrict__ cf,
                          float* __restrict__ out){
  int t = threadIdx.x, w = t >> 6, l = t & 63;
  int arow = blockIdx.x*64 + w*16 + (l & 15);
  const float* er = embf + (size_t)min(arow, NN-1)*EM;
  int kg = (l >> 4)*4;
  f4v acc[7];
  #pragma unroll
  for (int i = 0; i < 7; ++i) acc[i] = (f4v){0.f,0.f,0.f,0.f};
  #pragma unroll
  for (int ks = 0; ks < 2; ++ks){
    float4 a0 = *(const float4*)&er[ks*32 + kg];
    float4 a1 = *(const float4*)&er[ks*32 + 16 + kg];
    h8 af;
    af[0]=(_Float16)a0.x; af[1]=(_Float16)a0.y; af[2]=(_Float16)a0.z; af[3]=(_Float16)a0.w;
    af[4]=(_Float16)a1.x; af[5]=(_Float16)a1.y; af[6]=(_Float16)a1.z; af[7]=(_Float16)a1.w;
    const unsigned short* wb = cf + ((size_t)(ks*7)*64 + l)*8;
    #pragma unroll
    for (int nt = 0; nt < 7; ++nt){
      h8 bf = *(const h8*)(wb + (size_t)nt*64*8);
      acc[nt] = __builtin_amdgcn_mfma_f32_16x16x32_f16(af, bf, acc[nt], 0, 0, 0);
    }
  }
  int orow0 = blockIdx.x*64 + w*16 + (l >> 4)*4;
  int oc = l & 15;
  #pragma unroll
  for (int r = 0; r < 4; ++r){
    float lg[7];
    float mx = -1e30f;
    #pragma unroll
    for (int nt = 0; nt < 7; ++nt){
      int col = nt*16 + oc;
      lg[nt] = (col < KC) ? acc[nt][r] : -1e30f;
      mx = fmaxf(mx, lg[nt]);
    }
    #pragma unroll
    for (int off = 1; off <= 8; off <<= 1) mx = fmaxf(mx, __shfl_xor(mx, off));
    float ex[7];
    float ssum = 0.f;
    #pragma unroll
    for (int nt = 0; nt < 7; ++nt){
      int col = nt*16 + oc;
      ex[nt] = (col < KC) ? __expf(lg[nt] - mx) : 0.f;
      ssum += ex[nt];
    }
    #pragma unroll
    for (int off = 1; off <= 8; off <<= 1) ssum += __shfl_xor(ssum, off);
    float inv = 1.0f / ssum;
    int rr = orow0 + r;
    if (rr < NN){
      float* orow = out + (size_t)NN*EM + (size_t)rr*KC;
      #pragma unroll
      for (int nt = 0; nt < 7; ++nt){
        int col = nt*16 + oc;
        if (col < KC) orow[col] = ex[nt]*inv;
      }
    }
  }
}

// ---------------- launch ----------------
extern "C" void kernel_launch(void* const* d_in, const int* in_sizes, int n_in,
                              void* d_out, int out_size, void* d_ws, size_t ws_size,
                              hipStream_t stream){
  const float* x      = (const float*)d_in[0];
  const int*   ei     = (const int*)d_in[1];
  const float* W1     = (const float*)d_in[2];
  const float* b1     = (const float*)d_in[3];
  const float* gamma  = (const float*)d_in[4];
  const float* beta   = (const float*)d_in[5];
  const float* W2     = (const float*)d_in[6];
  const float* b2v    = (const float*)d_in[7];
  const float* ctr    = (const float*)d_in[8];
  const float* temp   = (const float*)d_in[9];
  float* out = (float*)d_out;

  // ws: dis[NN] | bufA[NN*HD floats] | bufB[NN*HD floats] | sums,sumsq[HD] |
  //     rowptr[NN+1] | esrc[EE] | gcur[256] | w1f | w2f | cf
  // pbuf (int2, 196*16384 = 25.7MB) overlays bufB; hg (bf16, 25.6MB) also in
  // bufB (pbuf dead after k_bfill2). h1s/h2s (bf16) in bufA.
  float* ws     = (float*)d_ws;
  float* dis    = ws;
  float* bufA   = dis + NN;
  float* bufB   = bufA + (size_t)NN*HD;
  float* sums   = bufB + (size_t)NN*HD;
  float* sumsq  = sums + HD;
  int*   rowptr = (int*)(sumsq + HD);
  int*   esrc   = rowptr + NN + 1;
  int*   gcur   = esrc + EE;
  unsigned short* w1f = (unsigned short*)(((uintptr_t)(gcur + 256) + 15) & ~(uintptr_t)15);
  unsigned short* w2f = w1f + 4*8*64*8;   // 16K halves
  unsigned short* cf  = w2f + 4*4*64*8;   // 8K halves, then 7K halves
  int2*  pbuf   = (int2*)bufB;

  unsigned short* h1s = (unsigned short*)bufA;
  unsigned short* hg  = (unsigned short*)bufB;
  unsigned short* h2s = (unsigned short*)bufA;

  k_wprep_all<<<16, 256, 0, stream>>>(W1, W2, ctr, temp, w1f, w2f, cf, gcur, sums, sumsq);
  k_part2  <<<(EE+2047)/2048, 256, 0, stream>>>(ei, gcur, pbuf);
  k_bfill2 <<<NBK, 256, 0, stream>>>(pbuf, gcur, rowptr, esrc, dis);

  k_gemm1  <<<(NN+63)/64, 256, 0, stream>>>(x, w1f, dis, h1s);
  k_gather1<<<NN/4, 256, 0, stream>>>(rowptr, esrc, dis, h1s, b1, hg);

  k_bn_stats<<<(NN+BN2_ROWS-1)/BN2_ROWS, 256, 0, stream>>>(hg, sums, sumsq);

  k_gemm2  <<<(NN+63)/64, 256, 0, stream>>>(hg, w2f, sums, sumsq, gamma, beta, dis, h2s);
  k_gather2<<<NN/4, 256, 0, stream>>>(rowptr, esrc, dis, h2s, b2v, out);

  k_softmax<<<(NN+63)/64, 256, 0, stream>>>(out, cf, out);
}